// Round 4
// baseline (177.557 us; speedup 1.0000x reference)
//
#include <hip/hip_runtime.h>

#define N_NODES 50000
#define N_EDGES 800000

// ws layout (in floats):
//  [0, 400000)        esr[node][8] (fallback path only)
//  [400000, 404096)   consts[k][32] (see precompute)
//  [404096, 404104)   scalars: {c, ce, wde0, wde1, wde2, pad...}
//  [404608, ...)      part_s[c][node][4] then part_r[c][node][4]
#define ESR_OFF    0
#define CONSTS_OFF 400000
#define SCAL_OFF   404096
#define PART_OFF   404608

#define NBINS      13
#define BINSZ      4000   // nodes per bin-side; LDS = 4000*4*4 = 64000 B; 2 blocks/CU
#define MAX_CHUNKS 20

__global__ void precompute_kernel(
    const float* __restrict__ g,      // globals_ [8]
    const float* __restrict__ W_en,   // [16][128]
    const float* __restrict__ b_en,   // [128]
    const float* __restrict__ W_ee,   // [3][128]
    const float* __restrict__ b_ee,   // [128]
    const float* __restrict__ W1,     // [392][128]
    const float* __restrict__ b1,     // [128]
    const float* __restrict__ W2,     // [128][128]
    const float* __restrict__ b2,     // [128]
    const float* __restrict__ W_dn,   // [128]
    const float* __restrict__ b_dn,   // [1]
    const float* __restrict__ W_de,   // [128]
    const float* __restrict__ b_de,   // [1]
    float* __restrict__ ws)
{
    const int s = blockIdx.x;
    const int k = threadIdx.x;
    float* consts = ws + CONSTS_OFF;
    float* scal   = ws + SCAL_OFF;

    if (s < 16) {
        float acc = 0.f;
        for (int l = 0; l < 128; ++l)
            acc += W_en[s * 128 + l] * W1[l * 128 + k];
        consts[k * 32 + s] = acc;
    } else if (s < 19) {
        const int j = s - 16;
        float acc = 0.f;
        for (int l = 0; l < 128; ++l)
            acc += W_ee[j * 128 + l] * W1[(128 + l) * 128 + k];
        consts[k * 32 + s] = acc;
    } else if (s < 22) {
        const int j = s - 19;
        float acc = 0.f;
        for (int l = 0; l < 128; ++l)
            acc += W_ee[j * 128 + l] * W1[(256 + l) * 128 + k];
        consts[k * 32 + s] = acc;
    } else if (s == 22) {
        float acc = b1[k];
        for (int l = 0; l < 128; ++l)
            acc += b_en[l] * W1[l * 128 + k];
        for (int j = 0; j < 8; ++j)
            acc += g[j] * W1[(384 + j) * 128 + k];
        consts[k * 32 + 22] = acc;
    } else if (s == 23) {
        float acc = 0.f;
        for (int l = 0; l < 128; ++l)
            acc += b_ee[l] * W1[(128 + l) * 128 + k];
        consts[k * 32 + 23] = acc;
    } else if (s == 24) {
        float acc = 0.f;
        for (int l = 0; l < 128; ++l)
            acc += b_ee[l] * W1[(256 + l) * 128 + k];
        consts[k * 32 + 24] = acc;
    } else if (s == 25) {
        float acc = 0.f;
        for (int j = 0; j < 128; ++j)
            acc += W2[k * 128 + j] * W_dn[j];
        consts[k * 32 + 25] = acc;
        consts[k * 32 + 26] = 0.f;
        consts[k * 32 + 27] = 0.f;
    } else {
        if (k == 0) {
            float c = b_dn[0];
            for (int j = 0; j < 128; ++j) c += b2[j] * W_dn[j];
            scal[0] = c;
            float ce = b_de[0];
            for (int l = 0; l < 128; ++l) ce += b_ee[l] * W_de[l];
            scal[1] = ce;
            scal[5] = 0.f; scal[6] = 0.f; scal[7] = 0.f;
        }
        if (k < 3) {
            float acc = 0.f;
            for (int l = 0; l < 128; ++l)
                acc += W_ee[k * 128 + l] * W_de[l];
            scal[2 + k] = acc;
        }
    }
}

// Pure streaming edge decoder.
__global__ __launch_bounds__(256) void edge_out_kernel(
    const float* __restrict__ edges,
    const float* __restrict__ ws,
    float* __restrict__ out_edges)
{
    const int e4 = (blockIdx.x * 256 + threadIdx.x) * 4;
    if (e4 >= N_EDGES) return;
    const float* scal = ws + SCAL_OFF;
    const float w0 = scal[2], w1 = scal[3], w2 = scal[4], cb = scal[1];
    const float4* ep = (const float4*)(edges + (size_t)e4 * 3);
    const float4 f0 = ep[0], f1 = ep[1], f2 = ep[2];
    float4 o;
    o.x = fmaf(f0.x, w0, fmaf(f0.y, w1, fmaf(f0.z, w2, cb)));
    o.y = fmaf(f0.w, w0, fmaf(f1.x, w1, fmaf(f1.y, w2, cb)));
    o.z = fmaf(f1.z, w0, fmaf(f1.w, w1, fmaf(f2.x, w2, cb)));
    o.w = fmaf(f2.y, w0, fmaf(f2.z, w1, fmaf(f2.w, w2, cb)));
    *(float4*)(out_edges + e4) = o;
}

// Split-side binned aggregation: blockIdx.y < NBINS -> sender side,
// else receiver side. Each block reads only ONE index array.
// 8 edges/thread; per-quad feature-load predicates.
__global__ __launch_bounds__(512) void agg_kernel(
    const float* __restrict__ edges,     // [E][3]
    const int*   __restrict__ senders,   // [E]
    const int*   __restrict__ receivers, // [E]
    float* __restrict__ part_s,          // [nchunks][N_NODES][4]
    float* __restrict__ part_r,          // [nchunks][N_NODES][4]
    int ce)                              // edges per chunk (multiple of 8)
{
    __shared__ float4 acc4[BINSZ];       // [BINSZ][4] floats = 64000 B
    float* acc = (float*)acc4;
    const int tid = threadIdx.x;
    for (int i = tid; i < BINSZ; i += 512)
        acc4[i] = make_float4(0.f, 0.f, 0.f, 0.f);
    __syncthreads();

    const int chunk  = blockIdx.x;
    const int binid  = blockIdx.y;
    const bool is_s  = binid < NBINS;
    const int bin    = is_s ? binid : binid - NBINS;
    const int lo     = bin * BINSZ;
    const int* __restrict__ idx = is_s ? senders : receivers;

    const int e_beg = chunk * ce;
    const int e_end = min(e_beg + ce, N_EDGES);
    for (int e8 = e_beg + tid * 8; e8 < e_end; e8 += 512 * 8) {
        const int4 ia = *(const int4*)(idx + e8);
        const int4 ib = *(const int4*)(idx + e8 + 4);
        const unsigned d0 = (unsigned)(ia.x - lo), d1 = (unsigned)(ia.y - lo);
        const unsigned d2 = (unsigned)(ia.z - lo), d3 = (unsigned)(ia.w - lo);
        const unsigned d4 = (unsigned)(ib.x - lo), d5 = (unsigned)(ib.y - lo);
        const unsigned d6 = (unsigned)(ib.z - lo), d7 = (unsigned)(ib.w - lo);
        if ((d0 < BINSZ) | (d1 < BINSZ) | (d2 < BINSZ) | (d3 < BINSZ)) {
            const float4* ep = (const float4*)(edges + (size_t)e8 * 3);
            const float4 f0 = ep[0], f1 = ep[1], f2 = ep[2];
            // e0: f0.x f0.y f0.z | e1: f0.w f1.x f1.y | e2: f1.z f1.w f2.x | e3: f2.y f2.z f2.w
            if (d0 < BINSZ) {
                atomicAdd(&acc[d0 * 4 + 0], f0.x); atomicAdd(&acc[d0 * 4 + 1], f0.y);
                atomicAdd(&acc[d0 * 4 + 2], f0.z); atomicAdd(&acc[d0 * 4 + 3], 1.0f);
            }
            if (d1 < BINSZ) {
                atomicAdd(&acc[d1 * 4 + 0], f0.w); atomicAdd(&acc[d1 * 4 + 1], f1.x);
                atomicAdd(&acc[d1 * 4 + 2], f1.y); atomicAdd(&acc[d1 * 4 + 3], 1.0f);
            }
            if (d2 < BINSZ) {
                atomicAdd(&acc[d2 * 4 + 0], f1.z); atomicAdd(&acc[d2 * 4 + 1], f1.w);
                atomicAdd(&acc[d2 * 4 + 2], f2.x); atomicAdd(&acc[d2 * 4 + 3], 1.0f);
            }
            if (d3 < BINSZ) {
                atomicAdd(&acc[d3 * 4 + 0], f2.y); atomicAdd(&acc[d3 * 4 + 1], f2.z);
                atomicAdd(&acc[d3 * 4 + 2], f2.w); atomicAdd(&acc[d3 * 4 + 3], 1.0f);
            }
        }
        if ((d4 < BINSZ) | (d5 < BINSZ) | (d6 < BINSZ) | (d7 < BINSZ)) {
            const float4* ep = (const float4*)(edges + (size_t)e8 * 3 + 12);
            const float4 f0 = ep[0], f1 = ep[1], f2 = ep[2];
            if (d4 < BINSZ) {
                atomicAdd(&acc[d4 * 4 + 0], f0.x); atomicAdd(&acc[d4 * 4 + 1], f0.y);
                atomicAdd(&acc[d4 * 4 + 2], f0.z); atomicAdd(&acc[d4 * 4 + 3], 1.0f);
            }
            if (d5 < BINSZ) {
                atomicAdd(&acc[d5 * 4 + 0], f0.w); atomicAdd(&acc[d5 * 4 + 1], f1.x);
                atomicAdd(&acc[d5 * 4 + 2], f1.y); atomicAdd(&acc[d5 * 4 + 3], 1.0f);
            }
            if (d6 < BINSZ) {
                atomicAdd(&acc[d6 * 4 + 0], f1.z); atomicAdd(&acc[d6 * 4 + 1], f1.w);
                atomicAdd(&acc[d6 * 4 + 2], f2.x); atomicAdd(&acc[d6 * 4 + 3], 1.0f);
            }
            if (d7 < BINSZ) {
                atomicAdd(&acc[d7 * 4 + 0], f2.y); atomicAdd(&acc[d7 * 4 + 1], f2.z);
                atomicAdd(&acc[d7 * 4 + 2], f2.w); atomicAdd(&acc[d7 * 4 + 3], 1.0f);
            }
        }
    }
    __syncthreads();

    float* base = (is_s ? part_s : part_r) + (size_t)chunk * (N_NODES * 4) + (size_t)lo * 4;
    const int lim = min(BINSZ, N_NODES - lo);
    float4* dst = (float4*)base;
    for (int i = tid; i < lim; i += 512)
        dst[i] = acc4[i];
}

// ---- fallback path (tiny ws): global-atomic scatter into esr[node][8] ----
__global__ __launch_bounds__(256) void edge_kernel_atomic(
    const float* __restrict__ edges,
    const int*   __restrict__ senders,
    const int*   __restrict__ receivers,
    float* __restrict__ ws)
{
    const int e = blockIdx.x * 256 + threadIdx.x;
    if (e >= N_EDGES) return;
    const float e0 = edges[e * 3 + 0];
    const float e1 = edges[e * 3 + 1];
    const float e2 = edges[e * 3 + 2];
    const int s = senders[e];
    const int r = receivers[e];
    float* esr = ws + ESR_OFF;
    atomicAdd(&esr[s * 8 + 0], e0);
    atomicAdd(&esr[s * 8 + 1], e1);
    atomicAdd(&esr[s * 8 + 2], e2);
    atomicAdd(&esr[s * 8 + 3], 1.0f);
    atomicAdd(&esr[r * 8 + 4], e0);
    atomicAdd(&esr[r * 8 + 5], e1);
    atomicAdd(&esr[r * 8 + 6], e2);
    atomicAdd(&esr[r * 8 + 7], 1.0f);
}

// Node MLP; nchunks>0: inline-reduce part_s/part_r, else read esr.
__global__ __launch_bounds__(256) void node_kernel(
    const float* __restrict__ nodes,  // [N][16]
    const float* __restrict__ ws,
    const float* __restrict__ part_s,
    const float* __restrict__ part_r,
    float* __restrict__ out_nodes,    // d_out
    int nchunks)
{
    __shared__ float4 lds4[128 * 8];  // consts[128][32] as float4[128][8], 16 KiB
    const float4* consts4 = (const float4*)(ws + CONSTS_OFF);
    for (int i = threadIdx.x; i < 128 * 8; i += 256)
        lds4[i] = consts4[i];
    __syncthreads();

    const int n = blockIdx.x * 256 + threadIdx.x;
    if (n >= N_NODES) return;

    const float4* np4 = (const float4*)(nodes + (size_t)n * 16);
    const float4 n0 = np4[0], n1 = np4[1], n2 = np4[2], n3 = np4[3];

    float4 es = make_float4(0.f, 0.f, 0.f, 0.f);
    float4 er = make_float4(0.f, 0.f, 0.f, 0.f);
    if (nchunks > 0) {
        for (int c = 0; c < nchunks; ++c) {
            const float4 a = *(const float4*)(part_s + (size_t)c * (N_NODES * 4) + (size_t)n * 4);
            const float4 b = *(const float4*)(part_r + (size_t)c * (N_NODES * 4) + (size_t)n * 4);
            es.x += a.x; es.y += a.y; es.z += a.z; es.w += a.w;
            er.x += b.x; er.y += b.y; er.z += b.z; er.w += b.w;
        }
    } else {
        const float4* p = (const float4*)(ws + ESR_OFF + (size_t)n * 8);
        es = p[0];
        er = p[1];
    }

    float acc = 0.f;
#pragma unroll 4
    for (int k = 0; k < 128; ++k) {
        const float4* c4 = &lds4[k * 8];
        const float4 m0 = c4[0], m1 = c4[1], m2 = c4[2], m3 = c4[3];
        const float4 q0 = c4[4];
        const float4 q1 = c4[5];
        const float4 q2 = c4[6];
        float pre = q1.z
            + n0.x * m0.x + n0.y * m0.y + n0.z * m0.z + n0.w * m0.w
            + n1.x * m1.x + n1.y * m1.y + n1.z * m1.z + n1.w * m1.w
            + n2.x * m2.x + n2.y * m2.y + n2.z * m2.z + n2.w * m2.w
            + n3.x * m3.x + n3.y * m3.y + n3.z * m3.z + n3.w * m3.w
            + es.x * q0.x + es.y * q0.y + es.z * q0.z
            + er.x * q0.w + er.y * q1.x + er.z * q1.y
            + es.w * q1.w + er.w * q2.x;
        acc += fmaxf(pre, 0.f) * q2.y;
    }
    const float* scal = ws + SCAL_OFF;
    out_nodes[n] = acc + scal[0];
}

extern "C" void kernel_launch(void* const* d_in, const int* in_sizes, int n_in,
                              void* d_out, int out_size, void* d_ws, size_t ws_size,
                              hipStream_t stream) {
    const float* nodes     = (const float*)d_in[0];
    const float* edges     = (const float*)d_in[1];
    const float* globals_  = (const float*)d_in[2];
    const int*   senders   = (const int*)d_in[3];
    const int*   receivers = (const int*)d_in[4];
    const float* W_en = (const float*)d_in[5];
    const float* b_en = (const float*)d_in[6];
    const float* W_ee = (const float*)d_in[7];
    const float* b_ee = (const float*)d_in[8];
    const float* W1   = (const float*)d_in[9];
    const float* b1   = (const float*)d_in[10];
    const float* W2   = (const float*)d_in[11];
    const float* b2   = (const float*)d_in[12];
    const float* W_dn = (const float*)d_in[13];
    const float* b_dn = (const float*)d_in[14];
    const float* W_de = (const float*)d_in[15];
    const float* b_de = (const float*)d_in[16];

    float* ws = (float*)d_ws;
    float* out = (float*)d_out;

    precompute_kernel<<<27, 128, 0, stream>>>(
        globals_, W_en, b_en, W_ee, b_ee, W1, b1, W2, b2,
        W_dn, b_dn, W_de, b_de, ws);

    edge_out_kernel<<<(N_EDGES / 4 + 255) / 256, 256, 0, stream>>>(
        edges, ws, out + N_NODES);

    long ws_floats = (long)(ws_size / 4);
    long per_chunk = 2L * N_NODES * 4;  // part_s + part_r copies
    long avail = (ws_floats - PART_OFF) / per_chunk;
    int nchunks = (int)(avail < 0 ? 0 : (avail > MAX_CHUNKS ? MAX_CHUNKS : avail));

    float* part_s = ws + PART_OFF;
    float* part_r = part_s + (size_t)nchunks * (N_NODES * 4);

    if (nchunks >= 1) {
        int ce = (N_EDGES + nchunks - 1) / nchunks;
        ce = (ce + 7) & ~7;  // keep 8-edge groups int4-aligned
        dim3 grid(nchunks, 2 * NBINS);
        agg_kernel<<<grid, 512, 0, stream>>>(
            edges, senders, receivers, part_s, part_r, ce);
    } else {
        hipMemsetAsync(ws + ESR_OFF, 0, (size_t)N_NODES * 8 * sizeof(float), stream);
        edge_kernel_atomic<<<(N_EDGES + 255) / 256, 256, 0, stream>>>(
            edges, senders, receivers, ws);
    }

    node_kernel<<<(N_NODES + 255) / 256, 256, 0, stream>>>(
        nodes, ws, part_s, part_r, out, nchunks);
}

// Round 5
// 174.503 us; speedup vs baseline: 1.0175x; 1.0175x over previous
//
#include <hip/hip_runtime.h>

#define N_NODES 50000
#define N_EDGES 800000

// ws layout (in floats):
//  [0, 400000)        esr[node][8] (fallback path only)
//  [400000, 404096)   consts[k][32] (see precompute)
//  [404096, 404104)   scalars: {c, ce, wde0, wde1, wde2, pad...}
//  [404608, ...)      part_s[c][node][4] then part_r[c][node][4]
#define ESR_OFF    0
#define CONSTS_OFF 400000
#define SCAL_OFF   404096
#define PART_OFF   404608

#define NBINS      25
#define BINSZ      2000   // nodes per bin-side; LDS = 2000*4*4 = 32000 B; 4 blocks/CU
#define MAX_CHUNKS 20

__global__ void precompute_kernel(
    const float* __restrict__ g,      // globals_ [8]
    const float* __restrict__ W_en,   // [16][128]
    const float* __restrict__ b_en,   // [128]
    const float* __restrict__ W_ee,   // [3][128]
    const float* __restrict__ b_ee,   // [128]
    const float* __restrict__ W1,     // [392][128]
    const float* __restrict__ b1,     // [128]
    const float* __restrict__ W2,     // [128][128]
    const float* __restrict__ b2,     // [128]
    const float* __restrict__ W_dn,   // [128]
    const float* __restrict__ b_dn,   // [1]
    const float* __restrict__ W_de,   // [128]
    const float* __restrict__ b_de,   // [1]
    float* __restrict__ ws)
{
    const int s = blockIdx.x;
    const int k = threadIdx.x;
    float* consts = ws + CONSTS_OFF;
    float* scal   = ws + SCAL_OFF;

    if (s < 16) {
        float acc = 0.f;
        for (int l = 0; l < 128; ++l)
            acc += W_en[s * 128 + l] * W1[l * 128 + k];
        consts[k * 32 + s] = acc;
    } else if (s < 19) {
        const int j = s - 16;
        float acc = 0.f;
        for (int l = 0; l < 128; ++l)
            acc += W_ee[j * 128 + l] * W1[(128 + l) * 128 + k];
        consts[k * 32 + s] = acc;
    } else if (s < 22) {
        const int j = s - 19;
        float acc = 0.f;
        for (int l = 0; l < 128; ++l)
            acc += W_ee[j * 128 + l] * W1[(256 + l) * 128 + k];
        consts[k * 32 + s] = acc;
    } else if (s == 22) {
        float acc = b1[k];
        for (int l = 0; l < 128; ++l)
            acc += b_en[l] * W1[l * 128 + k];
        for (int j = 0; j < 8; ++j)
            acc += g[j] * W1[(384 + j) * 128 + k];
        consts[k * 32 + 22] = acc;
    } else if (s == 23) {
        float acc = 0.f;
        for (int l = 0; l < 128; ++l)
            acc += b_ee[l] * W1[(128 + l) * 128 + k];
        consts[k * 32 + 23] = acc;
    } else if (s == 24) {
        float acc = 0.f;
        for (int l = 0; l < 128; ++l)
            acc += b_ee[l] * W1[(256 + l) * 128 + k];
        consts[k * 32 + 24] = acc;
    } else if (s == 25) {
        float acc = 0.f;
        for (int j = 0; j < 128; ++j)
            acc += W2[k * 128 + j] * W_dn[j];
        consts[k * 32 + 25] = acc;
        consts[k * 32 + 26] = 0.f;
        consts[k * 32 + 27] = 0.f;
    } else {
        if (k == 0) {
            float c = b_dn[0];
            for (int j = 0; j < 128; ++j) c += b2[j] * W_dn[j];
            scal[0] = c;
            float ce = b_de[0];
            for (int l = 0; l < 128; ++l) ce += b_ee[l] * W_de[l];
            scal[1] = ce;
            scal[5] = 0.f; scal[6] = 0.f; scal[7] = 0.f;
        }
        if (k < 3) {
            float acc = 0.f;
            for (int l = 0; l < 128; ++l)
                acc += W_ee[k * 128 + l] * W_de[l];
            scal[2 + k] = acc;
        }
    }
}

// Pure streaming edge decoder.
__global__ __launch_bounds__(256) void edge_out_kernel(
    const float* __restrict__ edges,
    const float* __restrict__ ws,
    float* __restrict__ out_edges)
{
    const int e4 = (blockIdx.x * 256 + threadIdx.x) * 4;
    if (e4 >= N_EDGES) return;
    const float* scal = ws + SCAL_OFF;
    const float w0 = scal[2], w1 = scal[3], w2 = scal[4], cb = scal[1];
    const float4* ep = (const float4*)(edges + (size_t)e4 * 3);
    const float4 f0 = ep[0], f1 = ep[1], f2 = ep[2];
    float4 o;
    o.x = fmaf(f0.x, w0, fmaf(f0.y, w1, fmaf(f0.z, w2, cb)));
    o.y = fmaf(f0.w, w0, fmaf(f1.x, w1, fmaf(f1.y, w2, cb)));
    o.z = fmaf(f1.z, w0, fmaf(f1.w, w1, fmaf(f2.x, w2, cb)));
    o.w = fmaf(f2.y, w0, fmaf(f2.z, w1, fmaf(f2.w, w2, cb)));
    *(float4*)(out_edges + e4) = o;
}

// Split-side binned aggregation, 32KB LDS -> 4 blocks/CU (32 waves/CU),
// 8 edges/thread with 1-deep index prefetch pipeline.
__global__ __launch_bounds__(512, 8) void agg_kernel(
    const float* __restrict__ edges,     // [E][3]
    const int*   __restrict__ senders,   // [E]
    const int*   __restrict__ receivers, // [E]
    float* __restrict__ part_s,          // [nchunks][N_NODES][4]
    float* __restrict__ part_r,          // [nchunks][N_NODES][4]
    int ce)                              // edges per chunk (multiple of 8)
{
    __shared__ float4 acc4[BINSZ];       // [BINSZ][4] floats = 32000 B
    float* acc = (float*)acc4;
    const int tid = threadIdx.x;
    for (int i = tid; i < BINSZ; i += 512)
        acc4[i] = make_float4(0.f, 0.f, 0.f, 0.f);
    __syncthreads();

    const int chunk  = blockIdx.x;
    const int binid  = blockIdx.y;
    const bool is_s  = binid < NBINS;
    const int bin    = is_s ? binid : binid - NBINS;
    const int lo     = bin * BINSZ;
    const int* __restrict__ idx = is_s ? senders : receivers;

    const int e_beg = chunk * ce;
    const int e_end = min(e_beg + ce, N_EDGES);
    const int STRIDE = 512 * 8;

    int e8 = e_beg + tid * 8;
    int4 ia = make_int4(-1, -1, -1, -1), ib = ia;
    if (e8 < e_end) {
        ia = *(const int4*)(idx + e8);
        ib = *(const int4*)(idx + e8 + 4);
    }
    while (e8 < e_end) {
        const int e8n = e8 + STRIDE;
        int4 ian = ia, ibn = ib;
        if (e8n < e_end) {                    // prefetch next iteration's indices
            ian = *(const int4*)(idx + e8n);
            ibn = *(const int4*)(idx + e8n + 4);
        }
        const unsigned d0 = (unsigned)(ia.x - lo), d1 = (unsigned)(ia.y - lo);
        const unsigned d2 = (unsigned)(ia.z - lo), d3 = (unsigned)(ia.w - lo);
        const unsigned d4 = (unsigned)(ib.x - lo), d5 = (unsigned)(ib.y - lo);
        const unsigned d6 = (unsigned)(ib.z - lo), d7 = (unsigned)(ib.w - lo);
        if ((d0 < BINSZ) | (d1 < BINSZ) | (d2 < BINSZ) | (d3 < BINSZ)) {
            const float4* ep = (const float4*)(edges + (size_t)e8 * 3);
            const float4 f0 = ep[0], f1 = ep[1], f2 = ep[2];
            // e0: f0.x f0.y f0.z | e1: f0.w f1.x f1.y | e2: f1.z f1.w f2.x | e3: f2.y f2.z f2.w
            if (d0 < BINSZ) {
                atomicAdd(&acc[d0 * 4 + 0], f0.x); atomicAdd(&acc[d0 * 4 + 1], f0.y);
                atomicAdd(&acc[d0 * 4 + 2], f0.z); atomicAdd(&acc[d0 * 4 + 3], 1.0f);
            }
            if (d1 < BINSZ) {
                atomicAdd(&acc[d1 * 4 + 0], f0.w); atomicAdd(&acc[d1 * 4 + 1], f1.x);
                atomicAdd(&acc[d1 * 4 + 2], f1.y); atomicAdd(&acc[d1 * 4 + 3], 1.0f);
            }
            if (d2 < BINSZ) {
                atomicAdd(&acc[d2 * 4 + 0], f1.z); atomicAdd(&acc[d2 * 4 + 1], f1.w);
                atomicAdd(&acc[d2 * 4 + 2], f2.x); atomicAdd(&acc[d2 * 4 + 3], 1.0f);
            }
            if (d3 < BINSZ) {
                atomicAdd(&acc[d3 * 4 + 0], f2.y); atomicAdd(&acc[d3 * 4 + 1], f2.z);
                atomicAdd(&acc[d3 * 4 + 2], f2.w); atomicAdd(&acc[d3 * 4 + 3], 1.0f);
            }
        }
        if ((d4 < BINSZ) | (d5 < BINSZ) | (d6 < BINSZ) | (d7 < BINSZ)) {
            const float4* ep = (const float4*)(edges + (size_t)e8 * 3 + 12);
            const float4 f0 = ep[0], f1 = ep[1], f2 = ep[2];
            if (d4 < BINSZ) {
                atomicAdd(&acc[d4 * 4 + 0], f0.x); atomicAdd(&acc[d4 * 4 + 1], f0.y);
                atomicAdd(&acc[d4 * 4 + 2], f0.z); atomicAdd(&acc[d4 * 4 + 3], 1.0f);
            }
            if (d5 < BINSZ) {
                atomicAdd(&acc[d5 * 4 + 0], f0.w); atomicAdd(&acc[d5 * 4 + 1], f1.x);
                atomicAdd(&acc[d5 * 4 + 2], f1.y); atomicAdd(&acc[d5 * 4 + 3], 1.0f);
            }
            if (d6 < BINSZ) {
                atomicAdd(&acc[d6 * 4 + 0], f1.z); atomicAdd(&acc[d6 * 4 + 1], f1.w);
                atomicAdd(&acc[d6 * 4 + 2], f2.x); atomicAdd(&acc[d6 * 4 + 3], 1.0f);
            }
            if (d7 < BINSZ) {
                atomicAdd(&acc[d7 * 4 + 0], f2.y); atomicAdd(&acc[d7 * 4 + 1], f2.z);
                atomicAdd(&acc[d7 * 4 + 2], f2.w); atomicAdd(&acc[d7 * 4 + 3], 1.0f);
            }
        }
        ia = ian; ib = ibn;
        e8 = e8n;
    }
    __syncthreads();

    float* base = (is_s ? part_s : part_r) + (size_t)chunk * (N_NODES * 4) + (size_t)lo * 4;
    float4* dst = (float4*)base;
    for (int i = tid; i < BINSZ; i += 512)
        dst[i] = acc4[i];
}

// ---- fallback path (tiny ws): global-atomic scatter into esr[node][8] ----
__global__ __launch_bounds__(256) void edge_kernel_atomic(
    const float* __restrict__ edges,
    const int*   __restrict__ senders,
    const int*   __restrict__ receivers,
    float* __restrict__ ws)
{
    const int e = blockIdx.x * 256 + threadIdx.x;
    if (e >= N_EDGES) return;
    const float e0 = edges[e * 3 + 0];
    const float e1 = edges[e * 3 + 1];
    const float e2 = edges[e * 3 + 2];
    const int s = senders[e];
    const int r = receivers[e];
    float* esr = ws + ESR_OFF;
    atomicAdd(&esr[s * 8 + 0], e0);
    atomicAdd(&esr[s * 8 + 1], e1);
    atomicAdd(&esr[s * 8 + 2], e2);
    atomicAdd(&esr[s * 8 + 3], 1.0f);
    atomicAdd(&esr[r * 8 + 4], e0);
    atomicAdd(&esr[r * 8 + 5], e1);
    atomicAdd(&esr[r * 8 + 6], e2);
    atomicAdd(&esr[r * 8 + 7], 1.0f);
}

// Node MLP. Consts are read with wave-uniform addresses straight from global
// memory (no LDS) -> compiler emits scalar (s_load) reads into SGPRs; FMAs
// take one SGPR operand. 64-thread blocks cover all CUs.
__global__ __launch_bounds__(64) void node_kernel(
    const float* __restrict__ nodes,  // [N][16]
    const float* __restrict__ ws,
    const float* __restrict__ part_s,
    const float* __restrict__ part_r,
    float* __restrict__ out_nodes,    // d_out
    int nchunks)
{
    const int n = blockIdx.x * 64 + threadIdx.x;
    if (n >= N_NODES) return;

    const float4* np4 = (const float4*)(nodes + (size_t)n * 16);
    const float4 n0 = np4[0], n1 = np4[1], n2 = np4[2], n3 = np4[3];

    float4 es = make_float4(0.f, 0.f, 0.f, 0.f);
    float4 er = make_float4(0.f, 0.f, 0.f, 0.f);
    if (nchunks > 0) {
        for (int c = 0; c < nchunks; ++c) {
            const float4 a = *(const float4*)(part_s + (size_t)c * (N_NODES * 4) + (size_t)n * 4);
            const float4 b = *(const float4*)(part_r + (size_t)c * (N_NODES * 4) + (size_t)n * 4);
            es.x += a.x; es.y += a.y; es.z += a.z; es.w += a.w;
            er.x += b.x; er.y += b.y; er.z += b.z; er.w += b.w;
        }
    } else {
        const float4* p = (const float4*)(ws + ESR_OFF + (size_t)n * 8);
        es = p[0];
        er = p[1];
    }

    const float* cst = ws + CONSTS_OFF;  // wave-uniform reads below
    float acc = 0.f;
#pragma unroll 4
    for (int k = 0; k < 128; ++k) {
        const float4 m0 = *(const float4*)(cst + k * 32 + 0);
        const float4 m1 = *(const float4*)(cst + k * 32 + 4);
        const float4 m2 = *(const float4*)(cst + k * 32 + 8);
        const float4 m3 = *(const float4*)(cst + k * 32 + 12);
        const float4 q0 = *(const float4*)(cst + k * 32 + 16);
        const float4 q1 = *(const float4*)(cst + k * 32 + 20);
        const float4 q2 = *(const float4*)(cst + k * 32 + 24);
        float pre = q1.z
            + n0.x * m0.x + n0.y * m0.y + n0.z * m0.z + n0.w * m0.w
            + n1.x * m1.x + n1.y * m1.y + n1.z * m1.z + n1.w * m1.w
            + n2.x * m2.x + n2.y * m2.y + n2.z * m2.z + n2.w * m2.w
            + n3.x * m3.x + n3.y * m3.y + n3.z * m3.z + n3.w * m3.w
            + es.x * q0.x + es.y * q0.y + es.z * q0.z
            + er.x * q0.w + er.y * q1.x + er.z * q1.y
            + es.w * q1.w + er.w * q2.x;
        acc += fmaxf(pre, 0.f) * q2.y;
    }
    const float* scal = ws + SCAL_OFF;
    out_nodes[n] = acc + scal[0];
}

extern "C" void kernel_launch(void* const* d_in, const int* in_sizes, int n_in,
                              void* d_out, int out_size, void* d_ws, size_t ws_size,
                              hipStream_t stream) {
    const float* nodes     = (const float*)d_in[0];
    const float* edges     = (const float*)d_in[1];
    const float* globals_  = (const float*)d_in[2];
    const int*   senders   = (const int*)d_in[3];
    const int*   receivers = (const int*)d_in[4];
    const float* W_en = (const float*)d_in[5];
    const float* b_en = (const float*)d_in[6];
    const float* W_ee = (const float*)d_in[7];
    const float* b_ee = (const float*)d_in[8];
    const float* W1   = (const float*)d_in[9];
    const float* b1   = (const float*)d_in[10];
    const float* W2   = (const float*)d_in[11];
    const float* b2   = (const float*)d_in[12];
    const float* W_dn = (const float*)d_in[13];
    const float* b_dn = (const float*)d_in[14];
    const float* W_de = (const float*)d_in[15];
    const float* b_de = (const float*)d_in[16];

    float* ws = (float*)d_ws;
    float* out = (float*)d_out;

    precompute_kernel<<<27, 128, 0, stream>>>(
        globals_, W_en, b_en, W_ee, b_ee, W1, b1, W2, b2,
        W_dn, b_dn, W_de, b_de, ws);

    edge_out_kernel<<<(N_EDGES / 4 + 255) / 256, 256, 0, stream>>>(
        edges, ws, out + N_NODES);

    long ws_floats = (long)(ws_size / 4);
    long per_chunk = 2L * N_NODES * 4;  // part_s + part_r copies
    long avail = (ws_floats - PART_OFF) / per_chunk;
    int nchunks = (int)(avail < 0 ? 0 : (avail > MAX_CHUNKS ? MAX_CHUNKS : avail));

    float* part_s = ws + PART_OFF;
    float* part_r = part_s + (size_t)nchunks * (N_NODES * 4);

    if (nchunks >= 1) {
        int ce = (N_EDGES + nchunks - 1) / nchunks;
        ce = (ce + 7) & ~7;  // keep 8-edge groups int4-aligned
        dim3 grid(nchunks, 2 * NBINS);
        agg_kernel<<<grid, 512, 0, stream>>>(
            edges, senders, receivers, part_s, part_r, ce);
    } else {
        hipMemsetAsync(ws + ESR_OFF, 0, (size_t)N_NODES * 8 * sizeof(float), stream);
        edge_kernel_atomic<<<(N_EDGES + 255) / 256, 256, 0, stream>>>(
            edges, senders, receivers, ws);
    }

    node_kernel<<<(N_NODES + 63) / 64, 64, 0, stream>>>(
        nodes, ws, part_s, part_r, out, nchunks);
}